// Round 4
// baseline (27.032 us; speedup 1.0000x reference)
//
#include <hip/hip_runtime.h>

// ConfidanceLoss: iou_gt = windowed-any (5x5x5, zero-clipped) of batchVolume
// sampled at 8^3 cell centers; outputs = [confi, iou_gt, in_use] each [B,512],
// concatenated flat as float32.
//
// R4: ballot-based row-mask build. Per lane: any4 = any of its 4 voxels,
// first = voxel 0 (window [4c,4c+4] spills one voxel into the next nibble).
// Two 64-bit ballots replace the 3-deep ds_swizzle OR chain -> no lgkm waits
// in the streaming loop; one ds_write_b16 per 8 lanes.

constexpr int PN = 512;   // 8^3 cells per batch

__global__ __launch_bounds__(512) void confi_iou_kernel(
    const float* __restrict__ confi,   // [B, 512]
    const int*   __restrict__ vol,     // [B, 32, 32, 32]
    float*       __restrict__ out,     // [3, B, 512] flat
    int B)
{
    const int b = blockIdx.x;
    const int t = threadIdx.x;

    // msh16[i2][i1]: low byte = per-nibble "any" bits (a), high byte =
    // per-nibble "voxel0" bits (b), for row (i1,i2). +1 pad on inner dim.
    __shared__ unsigned short msh16[32][33];
    __shared__ unsigned short colOr16[8][33];  // OR over i2-window
    __shared__ unsigned short fin16[8][8];     // OR over i1-window

    const int* vb = vol + (size_t)b * 32768;

    const int q     = t & 255;          // int4 index within a slice
    const int i2row = q >> 3;           // row (i2) this lane's nibble is in
    const int half  = t >> 8;           // which of 2 slices this thread does
    const int jrow  = (t >> 3) & 7;     // byte index within this wave's ballot
    const bool writer = (t & 7) == 0;   // one writer per row-group of 8 lanes

    // slice s = 2*it + half; int4 q within slice
    const int4* p = reinterpret_cast<const int4*>(vb) + half * 256 + q;

    #pragma unroll 4
    for (int it = 0; it < 16; ++it) {
        const int4 v = p[it * 512];
        const bool any4  = (v.x | v.y | v.z | v.w) != 0;
        const bool first = v.x != 0;
        const unsigned long long ma = __ballot(any4);   // 8 rows x 8 nibbles
        const unsigned long long mb = __ballot(first);
        if (writer) {
            const unsigned a  = (unsigned)(ma >> (8 * jrow)) & 0xFFu;
            const unsigned bb = (unsigned)(mb >> (8 * jrow)) & 0xFFu;
            msh16[i2row][it * 2 + half] = (unsigned short)(a | (bb << 8));
        }
    }
    __syncthreads();

    // ---- stage A: OR over i2-window -> colOr16[c2][i1] ----
    if (t < 256) {
        const int c2 = t >> 5;
        const int i1 = t & 31;
        const int lo = 4 * c2;
        const int hi = (lo + 4 < 31) ? (lo + 4) : 31;
        unsigned acc = 0;
        #pragma unroll
        for (int i2 = lo; i2 <= hi; ++i2) acc |= msh16[i2][i1];
        colOr16[c2][i1] = (unsigned short)acc;
    }
    __syncthreads();

    // ---- stage B: OR over i1-window -> fin16[c1][c2] ----
    if (t < 64) {
        const int c1 = t >> 3;
        const int c2 = t & 7;
        const int lo = 4 * c1;
        const int hi = (lo + 4 < 31) ? (lo + 4) : 31;
        unsigned acc = 0;
        #pragma unroll
        for (int i1 = lo; i1 <= hi; ++i1) acc |= colOr16[c2][i1];
        fin16[c1][c2] = (unsigned short)acc;
    }
    __syncthreads();

    // ---- emit: j = c3*64 + c2*8 + c1 ----
    {
        const int j  = t;               // 512 threads = 512 cells
        const int c1 = j & 7;
        const int c2 = (j >> 3) & 7;
        const int c3 = j >> 6;
        const unsigned f  = fin16[c1][c2];
        const unsigned a  = f & 0xFFu;
        const unsigned bb = (f >> 8);
        // window c3 hits nibble c3 fully (a_c3) + voxel 0 of nibble c3+1
        const unsigned w = a | (bb >> 1);
        const float iou = ((w >> c3) & 1u) ? 1.0f : 0.0f;
        const int BP  = B * PN;
        const int idx = b * PN + j;
        out[idx]          = confi[idx];  // output 0: confi pass-through
        out[BP + idx]     = iou;         // output 1: iou_gt
        out[2 * BP + idx] = iou;         // output 2: in_use (read as f32)
    }
}

extern "C" void kernel_launch(void* const* d_in, const int* in_sizes, int n_in,
                              void* d_out, int out_size, void* d_ws, size_t ws_size,
                              hipStream_t stream) {
    // inputs: 0 shape_rlt, 1 trans_rlt, 2 quat_rlt, 3 confi_rlt [B,512,1],
    //         4 batchVolume [B,32,32,32] int32
    const float* confi = (const float*)d_in[3];
    const int*   vol   = (const int*)d_in[4];
    float*       out   = (float*)d_out;
    const int B = in_sizes[4] / 32768;
    confi_iou_kernel<<<B, 512, 0, stream>>>(confi, vol, out, B);
}

// Round 5
// 26.973 us; speedup vs baseline: 1.0022x; 1.0022x over previous
//
#include <hip/hip_runtime.h>

// ConfidanceLoss: iou_gt = windowed-any (5x5x5, zero-clipped) of batchVolume
// sampled at 8^3 cell centers; outputs = [confi, iou_gt, in_use] each [B,512].
//
// R5: pure-streaming loop. Each thread owns 4 i1-quads at a fixed q (q encodes
// i2 row + i3 nibble); the 16 loads are independent with only register-OR
// accumulation between them (no ballot/LDS/exec ops in the loop). Per quad we
// keep {quad-any, quad-first, slice0-any, slice0-first}; slice0 terms supply
// the i1-window's one-slice spill into the next quad, mirroring the i3-nibble
// spill handled by the "first" predicate.

constexpr int PN = 512;   // 8^3 cells per batch

__global__ __launch_bounds__(512) void confi_iou_kernel(
    const float* __restrict__ confi,   // [B, 512]
    const int*   __restrict__ vol,     // [B, 32, 32, 32]
    float*       __restrict__ out,     // [3, B, 512] flat
    int B)
{
    const int b = blockIdx.x;
    const int t = threadIdx.x;

    // qmask[g][i2]: packed bytes {QA | QF<<8 | SA<<16 | SF<<24} for i1-quad g.
    // QA/QF: OR over the quad's 4 slices; SA/SF: the quad's first slice only.
    // A-bits: nibble-any per i3 nibble; F-bits: voxel-0-of-nibble per nibble.
    __shared__ unsigned qmask[8][33];
    __shared__ unsigned colQ[8][9];    // i2-window reduced: [g][c2]

    const int* vb = vol + (size_t)b * 32768;
    const int q     = t & 255;          // 8 i2-rows x 8 nibbles x ... (q>>3 = i2)
    const int gbase = (t >> 8) * 4;     // quads {gbase..gbase+3} owned by thread
    const int4* p = reinterpret_cast<const int4*>(vb) + gbase * 1024 + q;
    // slice i1 = 4*(gbase+g) + s  ->  int4 offset (4*g+s)*256 from p

    unsigned qa[4], qf[4], sa[4], sf[4];
    #pragma unroll
    for (int g = 0; g < 4; ++g) {
        qa[g] = 0; qf[g] = 0; sa[g] = 0; sf[g] = 0;
        #pragma unroll
        for (int s = 0; s < 4; ++s) {
            const int4 v = p[(g * 4 + s) * 256];
            const unsigned any = (unsigned)(v.x | v.y | v.z | v.w);
            const unsigned fst = (unsigned)v.x;
            qa[g] |= any; qf[g] |= fst;
            if (s == 0) { sa[g] = any; sf[g] = fst; }
        }
    }

    // ---- post-loop: ballots assemble per-(quad, i2) packed masks ----
    const int jrow   = (t >> 3) & 7;    // byte index within this wave's ballot
    const bool wr    = (t & 7) == 0;    // one writer per 8-lane row group
    const int i2row  = q >> 3;
    #pragma unroll
    for (int g = 0; g < 4; ++g) {
        const unsigned long long ba = __ballot(qa[g] != 0);
        const unsigned long long bf = __ballot(qf[g] != 0);
        const unsigned long long bs = __ballot(sa[g] != 0);
        const unsigned long long bt = __ballot(sf[g] != 0);
        if (wr) {
            const unsigned A = (unsigned)(ba >> (8 * jrow)) & 0xFFu;
            const unsigned F = (unsigned)(bf >> (8 * jrow)) & 0xFFu;
            const unsigned S = (unsigned)(bs >> (8 * jrow)) & 0xFFu;
            const unsigned T = (unsigned)(bt >> (8 * jrow)) & 0xFFu;
            qmask[gbase + g][i2row] = A | (F << 8) | (S << 16) | (T << 24);
        }
    }
    __syncthreads();

    // ---- i2-window OR (byte-wise safe) -> colQ[g][c2] ----
    if (t < 64) {
        const int g  = t >> 3;
        const int c2 = t & 7;
        const int lo = 4 * c2;
        const int hi = (lo + 4 < 31) ? (lo + 4) : 31;
        unsigned acc = 0;
        #pragma unroll
        for (int i2 = lo; i2 <= hi; ++i2) acc |= qmask[g][i2];
        colQ[g][c2] = acc;
    }
    __syncthreads();

    // ---- emit: j = c3*64 + c2*8 + c1 ----
    {
        const int j  = t;
        const int c1 = j & 7;
        const int c2 = (j >> 3) & 7;
        const int c3 = j >> 6;
        const unsigned u  = colQ[c1][c2];
        const unsigned un = (c1 < 7) ? colQ[c1 + 1][c2] : 0u;
        // i1-window = quad c1 OR first-slice-of-quad c1+1
        const unsigned RA = (u & 0xFFu)        | ((un >> 16) & 0xFFu);
        const unsigned RF = ((u >> 8) & 0xFFu) | ((un >> 24) & 0xFFu);
        // i3-window c3 = nibble c3 any  OR  voxel0 of nibble c3+1
        const unsigned W  = RA | (RF >> 1);
        const float iou = ((W >> c3) & 1u) ? 1.0f : 0.0f;
        const int BP  = B * PN;
        const int idx = b * PN + j;
        out[idx]          = confi[idx];  // output 0: confi pass-through
        out[BP + idx]     = iou;         // output 1: iou_gt
        out[2 * BP + idx] = iou;         // output 2: in_use (read as f32)
    }
}

extern "C" void kernel_launch(void* const* d_in, const int* in_sizes, int n_in,
                              void* d_out, int out_size, void* d_ws, size_t ws_size,
                              hipStream_t stream) {
    // inputs: 0 shape_rlt, 1 trans_rlt, 2 quat_rlt, 3 confi_rlt [B,512,1],
    //         4 batchVolume [B,32,32,32] int32
    const float* confi = (const float*)d_in[3];
    const int*   vol   = (const int*)d_in[4];
    float*       out   = (float*)d_out;
    const int B = in_sizes[4] / 32768;
    confi_iou_kernel<<<B, 512, 0, stream>>>(confi, vol, out, B);
}